// Round 4
// baseline (1763.976 us; speedup 1.0000x reference)
//
#include <hip/hip_runtime.h>
#include <math.h>

#define N_ROWS (32 * 64 * 64)   // 131072 rows
#define KCODES 1024
#define DIM 64
#define SKS 4                   // code-splits for screening
#define CPB 256                 // codes per screen block
#define TILES (CPB / 32)        // 8 code-tiles of 32

typedef __attribute__((ext_vector_type(8))) _Float16 f16x8;
typedef __attribute__((ext_vector_type(16))) float f32x16;
typedef unsigned long long u64;
typedef unsigned int u32;

// d_ws layout:
//   0        double loss_sum
//   8        u32 bnmax (float bits, positive -> u32-monotone)
//   12       u32 flag_count
//   16       int counts[1024]            (-> 4112)
//   4352     float bn[1024]              (-> 8448)
//   16384    _Float16 emb16[1024][64]    (scaled x256) (-> 147456)
//   147456   u64 wsbest[SKS][N_ROWS]     (4 MB)
//   4341760  u32 wssec[SKS][N_ROWS]      (2 MB)
//   6438912  u32 flaglist[N_ROWS]        (512 KB) -> 6963200 total
#define WS_BNMAX_OFF   8
#define WS_FLAGCNT_OFF 12
#define WS_COUNTS_OFF  16
#define WS_BN_OFF      4352
#define WS_E16_OFF     16384
#define WS_BEST_OFF    147456
#define WS_SEC_OFF     4341760
#define WS_FLIST_OFF   6438912
#define WS_ZERO_BYTES  4112

// ---------- prep: bn (exact chain, same as R1 bnorm), bnmax, scaled fp16 emb
__global__ void vq_prep(const float* __restrict__ emb,
                        float* __restrict__ bn,
                        _Float16* __restrict__ emb16,
                        u32* __restrict__ bnmax) {
    int c = blockIdx.x * blockDim.x + threadIdx.x;   // 4 blocks x 256
    const float* e = emb + c * DIM;
    float s = 0.f;
#pragma unroll
    for (int d = 0; d < DIM; ++d) s = fmaf(e[d], e[d], s);
    bn[c] = s;
    atomicMax(bnmax, __float_as_uint(s));
    _Float16* o = emb16 + (size_t)c * DIM;
#pragma unroll
    for (int d = 0; d < DIM; ++d) o[d] = (_Float16)(e[d] * 256.0f);
}

// ---------- screening: fp16 MFMA approx distances + best/second tracking
// v256 = 2048 + 128*bn - 256*dot ; argmin_k v  ==  argmin_k dist (an-free).
__launch_bounds__(256, 4)
__global__ void vq_screen(const float* __restrict__ x,
                          const _Float16* __restrict__ emb16,
                          const float* __restrict__ bn,
                          u64* __restrict__ wsbest,
                          u32* __restrict__ wssec) {
    const int kc = blockIdx.x >> 10;       // grid = SKS * 1024
    const int rb = blockIdx.x & 1023;
    const int c0 = kc * CPB;

    __shared__ __align__(16) char Blds[CPB * 128];   // swizzled fp16 codes
    __shared__ float bnh[CPB];                        // 2048 + 128*bn

    {   // stage: thread t -> code c0+t (128 B, XOR-swizzled 16B granules)
        int t = threadIdx.x;
        const uint4* src = (const uint4*)(emb16 + (size_t)(c0 + t) * DIM);
        char* dst = Blds + t * 128;
#pragma unroll
        for (int j = 0; j < 8; ++j) {
            uint4 v = src[j];
            *(uint4*)(dst + ((j * 16) ^ ((t & 7) << 4))) = v;
        }
        bnh[t] = fmaf(bn[c0 + t], 128.0f, 2048.0f);
    }
    __syncthreads();

    const int lane = threadIdx.x & 63;
    const int wid  = threadIdx.x >> 6;     // 4 waves x 32 rows
    const int lc   = lane & 31;            // A-row idx == B-col idx
    const int hi   = lane >> 5;
    const int row  = rb * 128 + wid * 32 + lc;

    // A fragments: slot j of k-step s holds x[row][16s + 8*hi + j]
    f16x8 afrag[4];
    {
        const float* xr = x + (size_t)row * DIM + hi * 8;
#pragma unroll
        for (int s = 0; s < 4; ++s) {
            float4 u0 = *(const float4*)(xr + s * 16);
            float4 u1 = *(const float4*)(xr + s * 16 + 4);
            f16x8 a;
            a[0] = (_Float16)u0.x; a[1] = (_Float16)u0.y;
            a[2] = (_Float16)u0.z; a[3] = (_Float16)u0.w;
            a[4] = (_Float16)u1.x; a[5] = (_Float16)u1.y;
            a[6] = (_Float16)u1.z; a[7] = (_Float16)u1.w;
            afrag[s] = a;
        }
    }

    u32 besthi_[16], bestcol_[16], sec_[16];
#pragma unroll
    for (int r = 0; r < 16; ++r) {
        besthi_[r] = 0x7F800000u; bestcol_[r] = 0u; sec_[r] = 0x7F800000u;
    }

    for (int t = 0; t < TILES; ++t) {
        const int cl = t * 32 + lc;                 // local code index
        float bnh8 = bnh[cl];
        const char* btile = Blds + cl * 128;
        const u32 sw = (u32)((cl & 7) << 4);
        f32x16 acc = {0.f,0.f,0.f,0.f, 0.f,0.f,0.f,0.f,
                      0.f,0.f,0.f,0.f, 0.f,0.f,0.f,0.f};
#pragma unroll
        for (int s = 0; s < 4; ++s) {
            f16x8 bf = *(const f16x8*)(btile + ((u32)(s * 32 + hi * 16) ^ sw));
            acc = __builtin_amdgcn_mfma_f32_32x32x16_f16(afrag[s], bf, acc, 0, 0, 0);
        }
        const u32 colg = (u32)(c0 + cl);
#pragma unroll
        for (int r = 0; r < 16; ++r) {
            float v = bnh8 - acc[r];
            u32 vb = __float_as_uint(v);          // v > 0 -> monotone bits
            u32 mx = vb > besthi_[r] ? vb : besthi_[r];
            sec_[r] = min(sec_[r], mx);
            if (vb < besthi_[r]) { besthi_[r] = vb; bestcol_[r] = colg; }
        }
    }

    // pack and butterfly-reduce across the 32 cols (lanes within hi half)
    u64 bp[16];
#pragma unroll
    for (int r = 0; r < 16; ++r) bp[r] = ((u64)besthi_[r] << 32) | bestcol_[r];
#pragma unroll
    for (int m = 1; m < 32; m <<= 1) {
#pragma unroll
        for (int r = 0; r < 16; ++r) {
            u64 o  = __shfl_xor(bp[r], m);
            u32 os = __shfl_xor(sec_[r], m);
            u32 oh = (u32)(o >> 32);
            u32 mh = (u32)(bp[r] >> 32);
            u32 mx = mh > oh ? mh : oh;
            sec_[r] = min(min(sec_[r], os), mx);
            if (o < bp[r]) bp[r] = o;
        }
    }
    if (lc == 0) {
        size_t base = (size_t)kc * N_ROWS + rb * 128 + wid * 32 + 4 * hi;
#pragma unroll
        for (int r = 0; r < 16; ++r) {
            size_t rr = base + (r & 3) + 8 * (r >> 2);
            wsbest[rr] = bp[r];
            wssec[rr]  = sec_[r];
        }
    }
}

// ---------- combine: certify or flag each row; gather decided rows
__launch_bounds__(256)
__global__ void vq_combine(const float* __restrict__ x,
                           const float* __restrict__ emb,
                           const u64* __restrict__ wsbest,
                           const u32* __restrict__ wssec,
                           const u32* __restrict__ bnmaxp,
                           float* __restrict__ out,
                           int* __restrict__ counts,
                           double* __restrict__ loss_sum,
                           u32* __restrict__ flagcnt,
                           u32* __restrict__ flaglist) {
    const int row = blockIdx.x * blockDim.x + threadIdx.x;

    u64 b0 = wsbest[row];
    u64 b1 = wsbest[(size_t)1 * N_ROWS + row];
    u64 b2 = wsbest[(size_t)2 * N_ROWS + row];
    u64 b3 = wsbest[(size_t)3 * N_ROWS + row];
    u32 s0 = wssec[row];
    u32 s1 = wssec[(size_t)1 * N_ROWS + row];
    u32 s2 = wssec[(size_t)2 * N_ROWS + row];
    u32 s3 = wssec[(size_t)3 * N_ROWS + row];

    u64 best = b0 < b1 ? b0 : b1;
    { u64 t2 = b2 < b3 ? b2 : b3; if (t2 < best) best = t2; }
    u32 h0 = (u32)(b0 >> 32), h1 = (u32)(b1 >> 32),
        h2 = (u32)(b2 >> 32), h3 = (u32)(b3 >> 32);
    u32 m1 = min(h0, h1), M1 = max(h0, h1);
    u32 m2 = min(h2, h3), M2 = max(h2, h3);
    u32 sec4 = min(max(m1, m2), min(M1, M2));
    u32 secall = min(min(min(s0, s1), min(s2, s3)), sec4);

    float bestv = __uint_as_float((u32)(best >> 32));
    float secv  = __uint_as_float(secall);

    const float* xp = x + (size_t)row * DIM;
    float a0 = 0.f, a1 = 0.f, a2 = 0.f, a3 = 0.f;
#pragma unroll
    for (int d = 0; d < DIM; d += 4) {
        float4 v = *(const float4*)(xp + d);
        a0 = fmaf(v.x, v.x, a0); a1 = fmaf(v.y, v.y, a1);
        a2 = fmaf(v.z, v.z, a2); a3 = fmaf(v.w, v.w, a3);
    }
    float an = (a0 + a1) + (a2 + a3);
    float bnm = __uint_as_float(*bnmaxp);
    // certification threshold in v256 units (theory ~0.25*sqrt; 4x safety)
    float T = fmaf(1.0f, sqrtf(an * bnm), 0.25f);

    float lsum = 0.f;
    bool flagged = (secv - bestv) <= T || an < 4.0f;
    if (flagged) {
        u32 idx = atomicAdd(flagcnt, 1u);
        flaglist[idx] = (u32)row;
    } else {
        const int bk = (int)(u32)best;
        const float* eb = emb + (size_t)bk * DIM;
        float* op = out + (size_t)row * DIM;
#pragma unroll
        for (int d = 0; d < DIM; d += 4) {
            float4 q = *(const float4*)(eb + d);
            float4 v = *(const float4*)(xp + d);
            *(float4*)(op + d) = q;
            float dx = q.x - v.x; lsum = fmaf(dx, dx, lsum);
            dx = q.y - v.y;       lsum = fmaf(dx, dx, lsum);
            dx = q.z - v.z;       lsum = fmaf(dx, dx, lsum);
            dx = q.w - v.w;       lsum = fmaf(dx, dx, lsum);
        }
        atomicAdd(&counts[bk], 1);
    }

    double dsum = (double)lsum;
#pragma unroll
    for (int off = 32; off > 0; off >>= 1) dsum += __shfl_down(dsum, off);
    __shared__ double red[4];
    const int lane = threadIdx.x & 63;
    const int wid  = threadIdx.x >> 6;
    if (lane == 0) red[wid] = dsum;
    __syncthreads();
    if (threadIdx.x == 0)
        atomicAdd(loss_sum, red[0] + red[1] + red[2] + red[3]);
}

// ---------- rescan: exact fp32 argmin (bit-identical to R1 formula) per row
__launch_bounds__(256)
__global__ void vq_rescan(const float* __restrict__ x,
                          const float* __restrict__ emb,
                          const float* __restrict__ bn,
                          const u32* __restrict__ flagcnt,
                          const u32* __restrict__ flaglist,
                          float* __restrict__ out,
                          int* __restrict__ counts,
                          double* __restrict__ loss_sum) {
    const int lane = threadIdx.x & 63;
    const int wv = (blockIdx.x * 256 + threadIdx.x) >> 6;   // 1024 waves
    const u32 n = *flagcnt;

    for (u32 i = wv; i < n; i += 1024) {
        const int row = (int)flaglist[i];
        const float* xp = x + (size_t)row * DIM;
        float xr[DIM];
#pragma unroll
        for (int d = 0; d < DIM; d += 4) {
            float4 v = *(const float4*)(xp + d);
            xr[d] = v.x; xr[d+1] = v.y; xr[d+2] = v.z; xr[d+3] = v.w;
        }
        float an = 0.f;   // sequential chain — matches R1
#pragma unroll
        for (int d = 0; d < DIM; ++d) an = fmaf(xr[d], xr[d], an);

        u64 best = ~0ull;
        for (int j = 0; j < 16; ++j) {
            const int k = j * 64 + lane;
            const float* ek = emb + (size_t)k * DIM;
            float q0 = 0.f, q1 = 0.f, q2 = 0.f, q3 = 0.f;
#pragma unroll
            for (int d = 0; d < DIM; d += 4) {
                q0 = fmaf(xr[d],     ek[d],     q0);
                q1 = fmaf(xr[d + 1], ek[d + 1], q1);
                q2 = fmaf(xr[d + 2], ek[d + 2], q2);
                q3 = fmaf(xr[d + 3], ek[d + 3], q3);
            }
            float dot = (q0 + q1) + (q2 + q3);
            float dist = fmaxf((an + bn[k]) - 2.0f * dot, 0.f);
            u64 p = ((u64)__float_as_uint(dist) << 32) | (u32)k;
            if (p < best) best = p;
        }
#pragma unroll
        for (int m = 1; m < 64; m <<= 1) {
            u64 o = __shfl_xor(best, m);
            if (o < best) best = o;
        }
        const int bk = (int)(u32)best;

        float q = emb[(size_t)bk * DIM + lane];
        float xv = xp[lane];
        out[(size_t)row * DIM + lane] = q;
        float dx = q - xv;
        double ds = (double)(dx * dx);
#pragma unroll
        for (int m = 1; m < 64; m <<= 1) ds += __shfl_xor(ds, m);
        if (lane == 0) {
            atomicAdd(loss_sum, ds);
            atomicAdd(&counts[bk], 1);
        }
    }
}

__global__ void vq_final_kernel(const int* __restrict__ counts,
                                const double* __restrict__ loss_sum,
                                float* __restrict__ out) {
    __shared__ double red[16];
    const int t = threadIdx.x;           // 1024 threads
    float p = (float)counts[t] / (float)N_ROWS;
    double term = (double)p * log((double)p + 1e-10);
#pragma unroll
    for (int off = 32; off > 0; off >>= 1) term += __shfl_down(term, off);
    if ((t & 63) == 0) red[t >> 6] = term;
    __syncthreads();
    if (t == 0) {
        double s = 0.0;
#pragma unroll
        for (int w = 0; w < 16; ++w) s += red[w];
        const size_t base = (size_t)N_ROWS * DIM;
        out[base]     = (float)(1.5 * (*loss_sum) / (double)((size_t)N_ROWS * DIM));
        out[base + 1] = (float)exp(-s);
    }
}

extern "C" void kernel_launch(void* const* d_in, const int* in_sizes, int n_in,
                              void* d_out, int out_size, void* d_ws, size_t ws_size,
                              hipStream_t stream) {
    const float* x   = (const float*)d_in[0];
    const float* emb = (const float*)d_in[1];
    float* out = (float*)d_out;

    char* ws = (char*)d_ws;
    double* loss_sum = (double*)ws;
    u32*  bnmax    = (u32*)(ws + WS_BNMAX_OFF);
    u32*  flagcnt  = (u32*)(ws + WS_FLAGCNT_OFF);
    int*  counts   = (int*)(ws + WS_COUNTS_OFF);
    float* bn      = (float*)(ws + WS_BN_OFF);
    _Float16* e16  = (_Float16*)(ws + WS_E16_OFF);
    u64*  wsbest   = (u64*)(ws + WS_BEST_OFF);
    u32*  wssec    = (u32*)(ws + WS_SEC_OFF);
    u32*  flist    = (u32*)(ws + WS_FLIST_OFF);

    hipMemsetAsync(d_ws, 0, WS_ZERO_BYTES, stream);

    vq_prep<<<KCODES / 256, 256, 0, stream>>>(emb, bn, e16, bnmax);
    vq_screen<<<SKS * 1024, 256, 0, stream>>>(x, e16, bn, wsbest, wssec);
    vq_combine<<<N_ROWS / 256, 256, 0, stream>>>(x, emb, wsbest, wssec, bnmax,
                                                 out, counts, loss_sum,
                                                 flagcnt, flist);
    vq_rescan<<<256, 256, 0, stream>>>(x, emb, bn, flagcnt, flist,
                                       out, counts, loss_sum);
    vq_final_kernel<<<1, 1024, 0, stream>>>(counts, loss_sum, out);
}

// Round 5
// 187.731 us; speedup vs baseline: 9.3963x; 9.3963x over previous
//
#include <hip/hip_runtime.h>
#include <math.h>

#define N_ROWS (32 * 64 * 64)   // 131072 rows
#define KCODES 1024
#define DIM 64
#define CPB 128                 // codes per LDS chunk
#define NCHUNK (KCODES / CPB)   // 8

typedef __attribute__((ext_vector_type(8))) _Float16 f16x8;
typedef __attribute__((ext_vector_type(16))) float f32x16;
typedef unsigned long long u64;
typedef unsigned int u32;

// d_ws layout:
//   0       double loss_sum
//   8       u32 flag_count
//   16      int counts[1024]           (-> 4112)  [zeroed]
//   4352    float bn[1024]             exact chain norms
//   8448    float nbh[1024]            -(512 + 128*bn)
//   16384   _Float16 ehi[1024*64]      fp16(256*e)
//   147456  _Float16 elo[1024*64]      fp16(256*e - ehi)
//   278528  u32 flaglist[N_ROWS]
#define WS_FLAGCNT_OFF 8
#define WS_COUNTS_OFF  16
#define WS_BN_OFF      4352
#define WS_NBH_OFF     8448
#define WS_EHI_OFF     16384
#define WS_ELO_OFF     147456
#define WS_FLIST_OFF   278528
#define WS_ZERO_BYTES  4112

// ---------- prep: exact bn, negated offset, split-fp16 codes
__global__ void vq_prep(const float* __restrict__ emb,
                        float* __restrict__ bn,
                        float* __restrict__ nbh,
                        _Float16* __restrict__ ehi,
                        _Float16* __restrict__ elo) {
    int c = blockIdx.x * blockDim.x + threadIdx.x;   // 4 blocks x 256
    const float* e = emb + c * DIM;
    float s = 0.f;
#pragma unroll
    for (int d = 0; d < DIM; ++d) s = fmaf(e[d], e[d], s);
    bn[c] = s;
    nbh[c] = -fmaf(s, 128.0f, 512.0f);
#pragma unroll
    for (int d = 0; d < DIM; ++d) {
        float v = e[d] * 256.0f;
        _Float16 h = (_Float16)v;
        ehi[(size_t)c * DIM + d] = h;
        elo[(size_t)c * DIM + d] = (_Float16)(v - (float)h);
    }
}

// ---------- screen: split-fp16 MFMA distances, full K, fused gather
// acc = dot256 - (512 + 128*bn)  (always negative); min dist == min u32 bits.
__launch_bounds__(256, 3)
__global__ void vq_screen(const float* __restrict__ x,
                          const _Float16* __restrict__ ehi,
                          const _Float16* __restrict__ elo,
                          const float* __restrict__ nbh,
                          const float* __restrict__ emb,
                          float* __restrict__ out,
                          int* __restrict__ counts,
                          double* __restrict__ loss_sum,
                          u32* __restrict__ flagcnt,
                          u32* __restrict__ flaglist) {
    __shared__ __align__(16) char H[CPB * 128];
    __shared__ __align__(16) char L[CPB * 128];
    __shared__ float NB[CPB];
    __shared__ u64 rowres[128];
    __shared__ float rowgap[128];
    __shared__ double red[4];

    const int rb   = blockIdx.x;          // 1024 blocks x 128 rows
    const int tid  = threadIdx.x;
    const int lane = tid & 63;
    const int wid  = tid >> 6;            // 4 waves x 32 rows
    const int lc   = lane & 31;
    const int hi   = lane >> 5;
    const int row  = rb * 128 + wid * 32 + lc;

    // A fragments: slot j of k-step s holds x[row][16s + 8hi + j], hi/lo split
    f16x8 ah[4], al[4];
    {
        const float* xr = x + (size_t)row * DIM + hi * 8;
#pragma unroll
        for (int s = 0; s < 4; ++s) {
            float4 u0 = *(const float4*)(xr + s * 16);
            float4 u1 = *(const float4*)(xr + s * 16 + 4);
            float v[8] = {u0.x, u0.y, u0.z, u0.w, u1.x, u1.y, u1.z, u1.w};
            f16x8 h8, l8;
#pragma unroll
            for (int j = 0; j < 8; ++j) {
                _Float16 h = (_Float16)v[j];
                h8[j] = h;
                l8[j] = (_Float16)(v[j] - (float)h);
            }
            ah[s] = h8; al[s] = l8;
        }
    }

    u32 bb[16], sec[16], bcol[16];
#pragma unroll
    for (int r = 0; r < 16; ++r) {
        bb[r] = 0xFFFFFFFFu; sec[r] = 0xFFFFFFFFu; bcol[r] = 0u;
    }

    for (int c = 0; c < NCHUNK; ++c) {
        {   // stage chunk: thread -> (code cl, 64B half), XOR-swizzled 16B granules
            const int cl = tid >> 1, half = tid & 1;
            const int code = c * CPB + cl;
            const uint4* sh = (const uint4*)(ehi + (size_t)code * DIM) + half * 4;
            const uint4* sl = (const uint4*)(elo + (size_t)code * DIM) + half * 4;
            char* dh = H + cl * 128;
            char* dl = L + cl * 128;
            const u32 sw = (u32)((cl & 7) << 4);
#pragma unroll
            for (int j = 0; j < 4; ++j) {
                const u32 off = (u32)(half * 64 + j * 16) ^ sw;
                *(uint4*)(dh + off) = sh[j];
                *(uint4*)(dl + off) = sl[j];
            }
            if (tid < CPB) NB[tid] = nbh[c * CPB + tid];
        }
        __syncthreads();

#pragma unroll
        for (int tt = 0; tt < CPB / 32; ++tt) {
            const int cl = tt * 32 + lc;
            const u32 sw = (u32)((cl & 7) << 4);
            const char* bh = H + cl * 128;
            const char* bl = L + cl * 128;
            const float nb = NB[cl];
            f32x16 acc;
#pragma unroll
            for (int r = 0; r < 16; ++r) acc[r] = nb;
#pragma unroll
            for (int s = 0; s < 4; ++s) {
                const u32 off = (u32)(s * 32 + hi * 16) ^ sw;
                f16x8 vh = *(const f16x8*)(bh + off);
                f16x8 vl = *(const f16x8*)(bl + off);
                acc = __builtin_amdgcn_mfma_f32_32x32x16_f16(ah[s], vh, acc, 0, 0, 0);
                acc = __builtin_amdgcn_mfma_f32_32x32x16_f16(ah[s], vl, acc, 0, 0, 0);
                acc = __builtin_amdgcn_mfma_f32_32x32x16_f16(al[s], vh, acc, 0, 0, 0);
            }
            const u32 colg = (u32)(c * CPB + cl);
#pragma unroll
            for (int r = 0; r < 16; ++r) {
                u32 vb = __float_as_uint(acc[r]);   // all negative: min bits = min dist
                u32 mx = vb > bb[r] ? vb : bb[r];
                sec[r] = min(sec[r], mx);
                if (vb < bb[r]) { bb[r] = vb; bcol[r] = colg; }
            }
        }
        __syncthreads();
    }

    // butterfly over the 32 cols; ties -> smaller col via packed u64 min
    u64 bp[16];
#pragma unroll
    for (int r = 0; r < 16; ++r) bp[r] = ((u64)bb[r] << 32) | bcol[r];
#pragma unroll
    for (int m = 1; m < 32; m <<= 1) {
#pragma unroll
        for (int r = 0; r < 16; ++r) {
            u64 o  = __shfl_xor(bp[r], m);
            u32 os = __shfl_xor(sec[r], m);
            u32 oh = (u32)(o >> 32);
            u32 mh = (u32)(bp[r] >> 32);
            u32 mx = mh > oh ? mh : oh;
            sec[r] = min(min(sec[r], os), mx);
            if (o < bp[r]) bp[r] = o;
        }
    }
    if (lc == 0) {
#pragma unroll
        for (int r = 0; r < 16; ++r) {
            const int rl = wid * 32 + 4 * hi + (r & 3) + 8 * (r >> 2);
            rowres[rl] = bp[r];
            // gap = acc_best - acc_sec (both negative floats), >= 0
            rowgap[rl] = __uint_as_float((u32)(bp[r] >> 32)) - __uint_as_float(sec[r]);
        }
    }
    __syncthreads();

    // gather: 2 threads per row (half each); certify or flag
    float lsum = 0.f;
    {
        const int rl = tid >> 1, half = tid & 1;
        const int grow = rb * 128 + rl;
        const float* xp = x + (size_t)grow * DIM + half * 32;

        float a0 = 0.f, a1 = 0.f, a2 = 0.f, a3 = 0.f;
#pragma unroll
        for (int d = 0; d < 32; d += 4) {
            float4 v = *(const float4*)(xp + d);
            a0 = fmaf(v.x, v.x, a0); a1 = fmaf(v.y, v.y, a1);
            a2 = fmaf(v.z, v.z, a2); a3 = fmaf(v.w, v.w, a3);
        }
        float ah_ = (a0 + a1) + (a2 + a3);
        float an = ah_ + __shfl_xor(ah_, 1);   // partner thread = other half

        const u64 res = rowres[rl];
        const float gap = rowgap[rl];
        const float T = fmaf(1e-4f, an, 0.004f);   // 2*screen_err + 2*ref_err + margin

        if (gap > T) {
            const int bk = (int)(u32)res;
            const float* eb = emb + (size_t)bk * DIM + half * 32;
            float* op = out + (size_t)grow * DIM + half * 32;
#pragma unroll
            for (int d = 0; d < 32; d += 4) {
                float4 q = *(const float4*)(eb + d);
                float4 v = *(const float4*)(xp + d);
                *(float4*)(op + d) = q;
                float dx = q.x - v.x; lsum = fmaf(dx, dx, lsum);
                dx = q.y - v.y;       lsum = fmaf(dx, dx, lsum);
                dx = q.z - v.z;       lsum = fmaf(dx, dx, lsum);
                dx = q.w - v.w;       lsum = fmaf(dx, dx, lsum);
            }
            if (half == 0) atomicAdd(&counts[bk], 1);
        } else if (half == 0) {
            u32 idx = atomicAdd(flagcnt, 1u);
            flaglist[idx] = (u32)grow;
        }
    }

    double dsum = (double)lsum;
#pragma unroll
    for (int off = 32; off > 0; off >>= 1) dsum += __shfl_down(dsum, off);
    if (lane == 0) red[wid] = dsum;
    __syncthreads();
    if (tid == 0)
        atomicAdd(loss_sum, red[0] + red[1] + red[2] + red[3]);
}

// ---------- rescan: exact fp32 argmin (R1 formula) for flagged rows
__launch_bounds__(256)
__global__ void vq_rescan(const float* __restrict__ x,
                          const float* __restrict__ emb,
                          const float* __restrict__ bn,
                          const u32* __restrict__ flagcnt,
                          const u32* __restrict__ flaglist,
                          float* __restrict__ out,
                          int* __restrict__ counts,
                          double* __restrict__ loss_sum) {
    const int lane = threadIdx.x & 63;
    const int wv = (blockIdx.x * 256 + threadIdx.x) >> 6;   // 1024 waves
    const u32 n = *flagcnt;

    for (u32 i = wv; i < n; i += 1024) {
        const int row = (int)flaglist[i];
        const float* xp = x + (size_t)row * DIM;
        float xr[DIM];
#pragma unroll
        for (int d = 0; d < DIM; d += 4) {
            float4 v = *(const float4*)(xp + d);
            xr[d] = v.x; xr[d+1] = v.y; xr[d+2] = v.z; xr[d+3] = v.w;
        }
        float an = 0.f;
#pragma unroll
        for (int d = 0; d < DIM; ++d) an = fmaf(xr[d], xr[d], an);

        u64 best = ~0ull;
        for (int j = 0; j < 16; ++j) {
            const int k = j * 64 + lane;
            const float* ek = emb + (size_t)k * DIM;
            float q0 = 0.f, q1 = 0.f, q2 = 0.f, q3 = 0.f;
#pragma unroll
            for (int d = 0; d < DIM; d += 4) {
                q0 = fmaf(xr[d],     ek[d],     q0);
                q1 = fmaf(xr[d + 1], ek[d + 1], q1);
                q2 = fmaf(xr[d + 2], ek[d + 2], q2);
                q3 = fmaf(xr[d + 3], ek[d + 3], q3);
            }
            float dot = (q0 + q1) + (q2 + q3);
            float dist = fmaxf((an + bn[k]) - 2.0f * dot, 0.f);
            u64 p = ((u64)__float_as_uint(dist) << 32) | (u32)k;
            if (p < best) best = p;
        }
#pragma unroll
        for (int m = 1; m < 64; m <<= 1) {
            u64 o = __shfl_xor(best, m);
            if (o < best) best = o;
        }
        const int bk = (int)(u32)best;

        float q = emb[(size_t)bk * DIM + lane];
        float xv = xp[lane];
        out[(size_t)row * DIM + lane] = q;
        float dx = q - xv;
        double ds = (double)(dx * dx);
#pragma unroll
        for (int m = 1; m < 64; m <<= 1) ds += __shfl_xor(ds, m);
        if (lane == 0) {
            atomicAdd(loss_sum, ds);
            atomicAdd(&counts[bk], 1);
        }
    }
}

__global__ void vq_final_kernel(const int* __restrict__ counts,
                                const double* __restrict__ loss_sum,
                                float* __restrict__ out) {
    __shared__ double red[16];
    const int t = threadIdx.x;           // 1024 threads
    float p = (float)counts[t] / (float)N_ROWS;
    double term = (double)p * log((double)p + 1e-10);
#pragma unroll
    for (int off = 32; off > 0; off >>= 1) term += __shfl_down(term, off);
    if ((t & 63) == 0) red[t >> 6] = term;
    __syncthreads();
    if (t == 0) {
        double s = 0.0;
#pragma unroll
        for (int w = 0; w < 16; ++w) s += red[w];
        const size_t base = (size_t)N_ROWS * DIM;
        out[base]     = (float)(1.5 * (*loss_sum) / (double)((size_t)N_ROWS * DIM));
        out[base + 1] = (float)exp(-s);
    }
}

extern "C" void kernel_launch(void* const* d_in, const int* in_sizes, int n_in,
                              void* d_out, int out_size, void* d_ws, size_t ws_size,
                              hipStream_t stream) {
    const float* x   = (const float*)d_in[0];
    const float* emb = (const float*)d_in[1];
    float* out = (float*)d_out;

    char* ws = (char*)d_ws;
    double* loss_sum = (double*)ws;
    u32*  flagcnt  = (u32*)(ws + WS_FLAGCNT_OFF);
    int*  counts   = (int*)(ws + WS_COUNTS_OFF);
    float* bn      = (float*)(ws + WS_BN_OFF);
    float* nbh     = (float*)(ws + WS_NBH_OFF);
    _Float16* ehi  = (_Float16*)(ws + WS_EHI_OFF);
    _Float16* elo  = (_Float16*)(ws + WS_ELO_OFF);
    u32*  flist    = (u32*)(ws + WS_FLIST_OFF);

    hipMemsetAsync(d_ws, 0, WS_ZERO_BYTES, stream);

    vq_prep<<<KCODES / 256, 256, 0, stream>>>(emb, bn, nbh, ehi, elo);
    vq_screen<<<N_ROWS / 128, 256, 0, stream>>>(x, ehi, elo, nbh, emb, out,
                                                counts, loss_sum, flagcnt, flist);
    vq_rescan<<<256, 256, 0, stream>>>(x, emb, bn, flagcnt, flist,
                                       out, counts, loss_sum);
    vq_final_kernel<<<1, 1024, 0, stream>>>(counts, loss_sum, out);
}